// Round 11
// baseline (322.252 us; speedup 1.0000x reference)
//
#include <hip/hip_runtime.h>
#include <hip/hip_bf16.h>
#include <hip/hip_fp16.h>

// Problem constants (from reference)
#define NODES 50000
#define NEDGE 800000
#define NE2   850000   // NEDGE + NODES self-loops
#define INDIM 128
#define F1    256      // HEADS*HID
#define HEADS 4
#define HID   64
#define OUTD  64
#define NBLK_SCAN 196  // ceil(NODES/256)
#define MTILES 3125    // NODES/16

typedef _Float16 f16;
typedef _Float16 f16x8 __attribute__((ext_vector_type(8)));
typedef float    f32x4 __attribute__((ext_vector_type(4)));

// ================= CSR hist + W pre-swizzle (merged, independent work) ======
__global__ void k_histprep(const int* __restrict__ ei, int* __restrict__ deg,
                           const float* __restrict__ W1, const float* __restrict__ W2,
                           f16* __restrict__ W1p, f16* __restrict__ W2p)
{
    const int b = blockIdx.x, t = threadIdx.x;
    if (b < 3125) {                       // 3125*256 == NEDGE exactly
        int i = b * 256 + t;
        atomicAdd(&deg[ei[NEDGE + i]], 1);
    } else {
        int idx = (b - 3125) * 256 + t;   // < 49152
        if (idx < 32768) {
            int j = idx & 7, l = (idx >> 3) & 63, fi = idx >> 9;
            int kb = fi & 3, ct = fi >> 2;
            int k = kb * 32 + (l >> 4) * 8 + j;
            int col = ct * 16 + (l & 15);
            W1p[idx] = (f16)W1[k * F1 + col];
        } else {
            int i2 = idx - 32768;         // < 16384
            int j = i2 & 7, l = (i2 >> 3) & 63, fi = i2 >> 9;
            int kb = fi & 7, ct = fi >> 3;
            int k = kb * 32 + (l >> 4) * 8 + j;
            int col = ct * 16 + (l & 15);
            W2p[i2] = (f16)W2[k * OUTD + col];
        }
    }
}

// per-256-chunk exclusive scan of (deg+1); chunk total to bsum
__global__ void k_scan1(const int* __restrict__ deg, int* __restrict__ excl,
                        int* __restrict__ bsum)
{
    __shared__ int sh[256];
    int t = threadIdx.x;
    int i = blockIdx.x * 256 + t;
    int v = (i < NODES) ? (deg[i] + 1) : 0;   // +1 = self loop
    sh[t] = v; __syncthreads();
    for (int off = 1; off < 256; off <<= 1) {
        int tv = (t >= off) ? sh[t - off] : 0;
        __syncthreads();
        sh[t] += tv;
        __syncthreads();
    }
    if (i < NODES) excl[i] = sh[t] - v;
    if (t == 255) bsum[blockIdx.x] = sh[255];
}

// add cross-chunk prefix (block-local reduction of bsum[0..bid)) + init cursor
__global__ void k_scan3(int* __restrict__ row_ptr, const int* __restrict__ bsum,
                        int* __restrict__ cursor)
{
    __shared__ int ssum[4];
    const int t = threadIdx.x, wv = t >> 6, lane = t & 63;
    int v = (t < (int)blockIdx.x) ? bsum[t] : 0;
#pragma unroll
    for (int off = 32; off; off >>= 1) v += __shfl_xor(v, off);
    if (lane == 0) ssum[wv] = v;
    __syncthreads();
    int prefix = ssum[0] + ssum[1] + ssum[2] + ssum[3];
    int i = blockIdx.x * 256 + t;
    if (i < NODES) {
        int r = row_ptr[i] + prefix;
        row_ptr[i] = r;
        cursor[i] = r;
    }
    if (i == 0) row_ptr[NODES] = NE2;
}

__global__ void k_scatter(const int* __restrict__ ei, int* __restrict__ cursor,
                          int* __restrict__ csr_src)
{
    int i = blockIdx.x * 256 + threadIdx.x;
    if (i >= NE2) return;
    int s, d;
    if (i < NEDGE) { s = ei[i]; d = ei[NEDGE + i]; } else { s = d = i - NEDGE; }
    int pos = atomicAdd(&cursor[d], 1);
    csr_src[pos] = s;
}

// ====== Layer 1 GEMM (MFMA) + fused attention scores =====================
__global__ __launch_bounds__(256) void k_gemm1m(
    const float* __restrict__ x, const f16* __restrict__ W1p,
    const float* __restrict__ as1, const float* __restrict__ ad1,
    f16* __restrict__ xp1h, float* __restrict__ ssrc, float* __restrict__ sdst)
{
    const int wv = threadIdx.x >> 6, lane = threadIdx.x & 63;
    const int l15 = lane & 15, quad = lane >> 4;
    const int rowtile = blockIdx.x * 4 + wv;
    if (rowtile >= MTILES) return;
    const int rowbase = rowtile * 16;

    f16x8 afrag[4];
    const float* xrow = x + (rowbase + l15) * INDIM + quad * 8;
#pragma unroll
    for (int kb = 0; kb < 4; ++kb) {
        float4 u0 = *(const float4*)(xrow + kb * 32);
        float4 u1 = *(const float4*)(xrow + kb * 32 + 4);
        f16x8 a;
        a[0] = (f16)u0.x; a[1] = (f16)u0.y; a[2] = (f16)u0.z; a[3] = (f16)u0.w;
        a[4] = (f16)u1.x; a[5] = (f16)u1.y; a[6] = (f16)u1.z; a[7] = (f16)u1.w;
        afrag[kb] = a;
    }

    const f16x8* Wf = (const f16x8*)W1p;
    f32x4 acc[16];
#pragma unroll
    for (int ct = 0; ct < 16; ++ct) acc[ct] = (f32x4){0.f, 0.f, 0.f, 0.f};
#pragma unroll
    for (int ct = 0; ct < 16; ++ct) {
#pragma unroll
        for (int kb = 0; kb < 4; ++kb) {
            f16x8 b = Wf[(ct * 4 + kb) * 64 + lane];
            acc[ct] = __builtin_amdgcn_mfma_f32_16x16x32_f16(afrag[kb], b, acc[ct], 0, 0, 0);
        }
    }
    // stores: C/D col = ct*16 + l15, row = quad*4 + r
    const int orow = rowbase + quad * 4;
#pragma unroll
    for (int ct = 0; ct < 16; ++ct) {
#pragma unroll
        for (int r = 0; r < 4; ++r)
            xp1h[(orow + r) * F1 + ct * 16 + l15] = (f16)acc[ct][r];
    }
    // fused scores
    float ps[4][4], pd[4][4];
#pragma unroll
    for (int h = 0; h < 4; ++h)
#pragma unroll
        for (int r = 0; r < 4; ++r) { ps[h][r] = 0.f; pd[h][r] = 0.f; }
#pragma unroll
    for (int ct = 0; ct < 16; ++ct) {
        float av = as1[ct * 16 + l15];
        float dv = ad1[ct * 16 + l15];
        int h = ct >> 2;
#pragma unroll
        for (int r = 0; r < 4; ++r) {
            ps[h][r] = fmaf(acc[ct][r], av, ps[h][r]);
            pd[h][r] = fmaf(acc[ct][r], dv, pd[h][r]);
        }
    }
#pragma unroll
    for (int off = 8; off; off >>= 1) {
#pragma unroll
        for (int h = 0; h < 4; ++h)
#pragma unroll
            for (int r = 0; r < 4; ++r) {
                ps[h][r] += __shfl_xor(ps[h][r], off);
                pd[h][r] += __shfl_xor(pd[h][r], off);
            }
    }
    if (l15 == 0) {
#pragma unroll
        for (int r = 0; r < 4; ++r) {
            int row = orow + r;
            float4 vs = {ps[0][r], ps[1][r], ps[2][r], ps[3][r]};
            float4 vd = {pd[0][r], pd[1][r], pd[2][r], pd[3][r]};
            ((float4*)ssrc)[row] = vs;
            ((float4*)sdst)[row] = vd;
        }
    }
}

// ===== Layer 1 agg: HEAD-SLICED for XCD-L2 affinity =====
// h = blockIdx&3: under round-robin block->XCD (%8), head h's blocks land on
// XCDs {h, h+4} only, so each XCD L2 streams just head h's 6.4 MB quarter of
// xp1h. Wave = one (node, head): 64-edge chunks; phase A lane=edge exp; phase
// B 8 edges/step x 8 lanes x 16B (agg2-proven structure), 2-step unroll.
__global__ __launch_bounds__(256) void k_agg1(
    const int* __restrict__ row_ptr, const int* __restrict__ csr_src,
    const float* __restrict__ ssrc, const float* __restrict__ sdst,
    const f16* __restrict__ xp1h, const float* __restrict__ bias,
    f16* __restrict__ hbuf)
{
    const int wv = threadIdx.x >> 6, l = threadIdx.x & 63;
    const int h = blockIdx.x & 3;
    const int n = (blockIdx.x >> 2) * 4 + wv;
    const int grp = l >> 3, sub = l & 7;
    const int hoff = h * 8;                    // f16x8 unit offset of head slice
    const float sd = sdst[n * HEADS + h];
    const int jbeg = row_ptr[n], jend = row_ptr[n + 1];
    const f16x8* xv = (const f16x8*)xp1h;

    float den = 0.f;
    float acc[8] = {0.f,0.f,0.f,0.f,0.f,0.f,0.f,0.f};
    for (int base = jbeg; base < jend; base += 64) {
        int c = jend - base; if (c > 64) c = 64;
        int s = 0; float ex = 0.f;
        if (l < c) {
            s = csr_src[base + l];
            float e = ssrc[s * HEADS + h] + sd;
            e = e > 0.f ? e : 0.2f * e;
            ex = __expf(e);
        }
        den += ex;
        int i = 0;
        for (; 8 * (i + 1) < c; i += 2) {
            int ea = 8 * i + grp, eb = 8 * i + 8 + grp;
            int   sa = __shfl(s, ea),  sb = __shfl(s, eb);
            float aa = __shfl(ex, ea), ab = __shfl(ex, eb);
            f16x8 va = xv[sa * 32 + hoff + sub];
            f16x8 vb = xv[sb * 32 + hoff + sub];
#pragma unroll
            for (int j = 0; j < 8; ++j) acc[j] = fmaf(aa, (float)va[j], acc[j]);
#pragma unroll
            for (int j = 0; j < 8; ++j) acc[j] = fmaf(ab, (float)vb[j], acc[j]);
        }
        for (; 8 * i < c; ++i) {
            int eidx = 8 * i + grp;
            int   se = __shfl(s, eidx);
            float ae = __shfl(ex, eidx);
            f16x8 v = xv[se * 32 + hoff + sub];
#pragma unroll
            for (int j = 0; j < 8; ++j) acc[j] = fmaf(ae, (float)v[j], acc[j]);
        }
    }
    // denominator for head h: full-wave reduce
#pragma unroll
    for (int off = 32; off; off >>= 1) den += __shfl_xor(den, off);
    const float rd = 1.f / (den + 1e-16f);
    // combine the 8 edge-groups
#pragma unroll
    for (int j = 0; j < 8; ++j) {
        acc[j] += __shfl_xor(acc[j], 8);
        acc[j] += __shfl_xor(acc[j], 16);
        acc[j] += __shfl_xor(acc[j], 32);
    }
    if (grp == 0) {
        const float4* b4 = (const float4*)bias;
        float4 ba = b4[(hoff + sub) * 2], bb = b4[(hoff + sub) * 2 + 1];
        f16x8 o;
        float v;
        v = fmaf(acc[0], rd, ba.x); o[0] = (f16)(v > 0.f ? v : 0.f);
        v = fmaf(acc[1], rd, ba.y); o[1] = (f16)(v > 0.f ? v : 0.f);
        v = fmaf(acc[2], rd, ba.z); o[2] = (f16)(v > 0.f ? v : 0.f);
        v = fmaf(acc[3], rd, ba.w); o[3] = (f16)(v > 0.f ? v : 0.f);
        v = fmaf(acc[4], rd, bb.x); o[4] = (f16)(v > 0.f ? v : 0.f);
        v = fmaf(acc[5], rd, bb.y); o[5] = (f16)(v > 0.f ? v : 0.f);
        v = fmaf(acc[6], rd, bb.z); o[6] = (f16)(v > 0.f ? v : 0.f);
        v = fmaf(acc[7], rd, bb.w); o[7] = (f16)(v > 0.f ? v : 0.f);
        ((f16x8*)hbuf)[n * 32 + hoff + sub] = o;
    }
}

// ====== Layer 2 GEMM (MFMA) + fused scores ================================
__global__ __launch_bounds__(256) void k_gemm2m(
    const f16* __restrict__ hbuf, const f16* __restrict__ W2p,
    const float* __restrict__ as2, const float* __restrict__ ad2,
    f16* __restrict__ xp2h, float* __restrict__ ssrc, float* __restrict__ sdst)
{
    const int wv = threadIdx.x >> 6, lane = threadIdx.x & 63;
    const int l15 = lane & 15, quad = lane >> 4;
    const int rowtile = blockIdx.x * 4 + wv;
    if (rowtile >= MTILES) return;
    const int rowbase = rowtile * 16;

    const f16x8* Wf = (const f16x8*)W2p;
    f32x4 acc[4];
#pragma unroll
    for (int ct = 0; ct < 4; ++ct) acc[ct] = (f32x4){0.f, 0.f, 0.f, 0.f};
    const f16* hrow = hbuf + (rowbase + l15) * F1 + quad * 8;
#pragma unroll
    for (int kb = 0; kb < 8; ++kb) {
        f16x8 a = *(const f16x8*)(hrow + kb * 32);
#pragma unroll
        for (int ct = 0; ct < 4; ++ct) {
            f16x8 b = Wf[(ct * 8 + kb) * 64 + lane];
            acc[ct] = __builtin_amdgcn_mfma_f32_16x16x32_f16(a, b, acc[ct], 0, 0, 0);
        }
    }
    const int orow = rowbase + quad * 4;
#pragma unroll
    for (int ct = 0; ct < 4; ++ct) {
#pragma unroll
        for (int r = 0; r < 4; ++r)
            xp2h[(orow + r) * OUTD + ct * 16 + l15] = (f16)acc[ct][r];
    }
    float ps[4] = {0.f,0.f,0.f,0.f}, pd[4] = {0.f,0.f,0.f,0.f};
#pragma unroll
    for (int ct = 0; ct < 4; ++ct) {
        float av = as2[ct * 16 + l15];
        float dv = ad2[ct * 16 + l15];
#pragma unroll
        for (int r = 0; r < 4; ++r) {
            ps[r] = fmaf(acc[ct][r], av, ps[r]);
            pd[r] = fmaf(acc[ct][r], dv, pd[r]);
        }
    }
#pragma unroll
    for (int off = 8; off; off >>= 1) {
#pragma unroll
        for (int r = 0; r < 4; ++r) {
            ps[r] += __shfl_xor(ps[r], off);
            pd[r] += __shfl_xor(pd[r], off);
        }
    }
    if (l15 == 0) {
#pragma unroll
        for (int r = 0; r < 4; ++r) {
            ssrc[orow + r] = ps[r];
            sdst[orow + r] = pd[r];
        }
    }
}

// ===== Layer 2 fused softmax+aggregate+bias -> d_out: b128 gather =====
// chunk = 64 edges; phase B 2-step unroll (2 gathers in flight per lane)
__global__ __launch_bounds__(256) void k_agg2(
    const int* __restrict__ row_ptr, const int* __restrict__ csr_src,
    const float* __restrict__ ssrc, const float* __restrict__ sdst,
    const f16* __restrict__ xp2h, const float* __restrict__ bias,
    float* __restrict__ out)
{
    const int wv = threadIdx.x >> 6, l = threadIdx.x & 63;
    const int n = blockIdx.x * 4 + wv;
    const int grp = l >> 3, sub = l & 7;
    const float sd = sdst[n];
    const int jbeg = row_ptr[n], jend = row_ptr[n + 1];
    const f16x8* xv = (const f16x8*)xp2h;

    float den = 0.f;
    float acc[8] = {0.f,0.f,0.f,0.f,0.f,0.f,0.f,0.f};
    for (int base = jbeg; base < jend; base += 64) {
        int c = jend - base; if (c > 64) c = 64;
        int s = 0; float ex = 0.f;
        if (l < c) {
            s = csr_src[base + l];
            float e = ssrc[s] + sd;
            e = e > 0.f ? e : 0.2f * e;
            ex = __expf(e);
        }
        den += ex;
        int i = 0;
        for (; 8 * (i + 1) < c; i += 2) {
            int ea = 8 * i + grp, eb = 8 * i + 8 + grp;
            int   sa = __shfl(s, ea),  sb = __shfl(s, eb);
            float aa = __shfl(ex, ea), ab = __shfl(ex, eb);
            f16x8 va = xv[sa * 8 + sub];
            f16x8 vb = xv[sb * 8 + sub];
#pragma unroll
            for (int j = 0; j < 8; ++j) acc[j] = fmaf(aa, (float)va[j], acc[j]);
#pragma unroll
            for (int j = 0; j < 8; ++j) acc[j] = fmaf(ab, (float)vb[j], acc[j]);
        }
        for (; 8 * i < c; ++i) {
            int eidx = 8 * i + grp;
            int   se = __shfl(s, eidx);
            float ae = __shfl(ex, eidx);
            f16x8 v = xv[se * 8 + sub];
#pragma unroll
            for (int j = 0; j < 8; ++j) acc[j] = fmaf(ae, (float)v[j], acc[j]);
        }
    }
#pragma unroll
    for (int off = 32; off; off >>= 1) den += __shfl_xor(den, off);
    const float rd = 1.f / (den + 1e-16f);
#pragma unroll
    for (int j = 0; j < 8; ++j) {
        acc[j] += __shfl_xor(acc[j], 8);
        acc[j] += __shfl_xor(acc[j], 16);
        acc[j] += __shfl_xor(acc[j], 32);
    }
    if (grp == 0) {
        const float4* b4 = (const float4*)bias;
        float4 ba = b4[sub * 2], bb = b4[sub * 2 + 1];
        float4 o0, o1;
        o0.x = fmaf(acc[0], rd, ba.x); o0.y = fmaf(acc[1], rd, ba.y);
        o0.z = fmaf(acc[2], rd, ba.z); o0.w = fmaf(acc[3], rd, ba.w);
        o1.x = fmaf(acc[4], rd, bb.x); o1.y = fmaf(acc[5], rd, bb.y);
        o1.z = fmaf(acc[6], rd, bb.z); o1.w = fmaf(acc[7], rd, bb.w);
        float4* ov = (float4*)out + n * 16 + sub * 2;
        ov[0] = o0; ov[1] = o1;
    }
}

extern "C" void kernel_launch(void* const* d_in, const int* in_sizes, int n_in,
                              void* d_out, int out_size, void* d_ws, size_t ws_size,
                              hipStream_t stream)
{
    (void)in_sizes; (void)n_in; (void)out_size; (void)ws_size;
    const float* x   = (const float*)d_in[0];
    const int*   ei  = (const int*)d_in[1];
    const float* W1  = (const float*)d_in[2];
    const float* as1 = (const float*)d_in[3];
    const float* ad1 = (const float*)d_in[4];
    const float* b1  = (const float*)d_in[5];
    const float* W2  = (const float*)d_in[6];
    const float* as2 = (const float*)d_in[7];
    const float* ad2 = (const float*)d_in[8];
    const float* b2  = (const float*)d_in[9];
    float* out = (float*)d_out;

    // workspace layout (~58 MB)
    f16* xp1h   = (f16*)d_ws;                              // N*256 f16 (25.6 MB)
    f16* hbuf   = xp1h + (size_t)NODES * F1;               // N*256 f16 (25.6 MB)
    f16* W1p    = hbuf + (size_t)NODES * F1;               // 32768 f16
    f16* W2p    = W1p + 32768;                             // 16384 f16
    float* ssrc1 = (float*)(W2p + 16384);                  // N*4
    float* sdst1 = ssrc1 + (size_t)NODES * HEADS;          // N*4
    float* ssrc2 = sdst1 + (size_t)NODES * HEADS;          // N
    float* sdst2 = ssrc2 + (size_t)NODES;                  // N
    int* deg     = (int*)(sdst2 + (size_t)NODES);          // N
    int* row_ptr = deg + NODES;                            // N+1
    int* bsum    = row_ptr + NODES + 1;                    // 256
    int* cursor  = bsum + 256;                             // N
    int* csr_src = cursor + NODES;                         // NE2
    f16* xp2h    = xp1h;   // alias: xp1h dead after k_agg1

    // ---- CSR build (dst-sorted) + W pre-swizzle ----
    hipMemsetAsync(deg, 0, sizeof(int) * NODES, stream);
    k_histprep<<<3125 + 192, 256, 0, stream>>>(ei, deg, W1, W2, W1p, W2p);
    k_scan1<<<NBLK_SCAN, 256, 0, stream>>>(deg, row_ptr, bsum);
    k_scan3<<<NBLK_SCAN, 256, 0, stream>>>(row_ptr, bsum, cursor);
    k_scatter<<<(NE2 + 255) / 256, 256, 0, stream>>>(ei, cursor, csr_src);

    // ---- layer 1 ----
    k_gemm1m<<<(MTILES + 3) / 4, 256, 0, stream>>>(x, W1p, as1, ad1,
                                                   xp1h, ssrc1, sdst1);
    k_agg1<<<NODES, 256, 0, stream>>>(row_ptr, csr_src, ssrc1, sdst1,
                                      xp1h, b1, hbuf);   // grid = 12500 node-groups x 4 heads

    // ---- layer 2 ----
    k_gemm2m<<<(MTILES + 3) / 4, 256, 0, stream>>>(hbuf, W2p, as2, ad2,
                                                   xp2h, ssrc2, sdst2);
    k_agg2<<<NODES / 4, 256, 0, stream>>>(row_ptr, csr_src, ssrc2, sdst2,
                                          xp2h, b2, out);
}

// Round 13
// 295.349 us; speedup vs baseline: 1.0911x; 1.0911x over previous
//
#include <hip/hip_runtime.h>
#include <hip/hip_bf16.h>
#include <hip/hip_fp16.h>

// Problem constants (from reference)
#define NODES 50000
#define NEDGE 800000
#define NE2   850000   // NEDGE + NODES self-loops
#define INDIM 128
#define F1    256      // HEADS*HID
#define HEADS 4
#define HID   64
#define OUTD  64
#define NBLK_SCAN 196  // ceil(NODES/256)
#define MTILES 3125    // NODES/16

typedef _Float16 f16;
typedef _Float16 f16x8 __attribute__((ext_vector_type(8)));
typedef float    f32x4 __attribute__((ext_vector_type(4)));

// ================= CSR hist + W pre-swizzle (merged, independent work) ======
__global__ void k_histprep(const int* __restrict__ ei, int* __restrict__ deg,
                           const float* __restrict__ W1, const float* __restrict__ W2,
                           f16* __restrict__ W1p, f16* __restrict__ W2p)
{
    const int b = blockIdx.x, t = threadIdx.x;
    if (b < 3125) {                       // 3125*256 == NEDGE exactly
        int i = b * 256 + t;
        atomicAdd(&deg[ei[NEDGE + i]], 1);
    } else {
        int idx = (b - 3125) * 256 + t;   // < 49152
        if (idx < 32768) {
            int j = idx & 7, l = (idx >> 3) & 63, fi = idx >> 9;
            int kb = fi & 3, ct = fi >> 2;
            int k = kb * 32 + (l >> 4) * 8 + j;
            int col = ct * 16 + (l & 15);
            W1p[idx] = (f16)W1[k * F1 + col];
        } else {
            int i2 = idx - 32768;         // < 16384
            int j = i2 & 7, l = (i2 >> 3) & 63, fi = i2 >> 9;
            int kb = fi & 7, ct = fi >> 3;
            int k = kb * 32 + (l >> 4) * 8 + j;
            int col = ct * 16 + (l & 15);
            W2p[i2] = (f16)W2[k * OUTD + col];
        }
    }
}

// per-256-chunk exclusive scan of (deg+1); chunk total to bsum
__global__ void k_scan1(const int* __restrict__ deg, int* __restrict__ excl,
                        int* __restrict__ bsum)
{
    __shared__ int sh[256];
    int t = threadIdx.x;
    int i = blockIdx.x * 256 + t;
    int v = (i < NODES) ? (deg[i] + 1) : 0;   // +1 = self loop
    sh[t] = v; __syncthreads();
    for (int off = 1; off < 256; off <<= 1) {
        int tv = (t >= off) ? sh[t - off] : 0;
        __syncthreads();
        sh[t] += tv;
        __syncthreads();
    }
    if (i < NODES) excl[i] = sh[t] - v;
    if (t == 255) bsum[blockIdx.x] = sh[255];
}

// cross-chunk prefix + init cursor; pre-place self-loop in csr_src slot 0
__global__ void k_scan3(int* __restrict__ row_ptr, const int* __restrict__ bsum,
                        int* __restrict__ cursor, int* __restrict__ csr_src)
{
    __shared__ int ssum[4];
    const int t = threadIdx.x, wv = t >> 6, lane = t & 63;
    int v = (t < (int)blockIdx.x) ? bsum[t] : 0;
#pragma unroll
    for (int off = 32; off; off >>= 1) v += __shfl_xor(v, off);
    if (lane == 0) ssum[wv] = v;
    __syncthreads();
    int prefix = ssum[0] + ssum[1] + ssum[2] + ssum[3];
    int i = blockIdx.x * 256 + t;
    if (i < NODES) {
        int r = row_ptr[i] + prefix;
        row_ptr[i] = r;
        csr_src[r] = i;        // self-loop occupies the first slot
        cursor[i] = r + 1;     // real edges scatter after it
    }
    if (i == 0) row_ptr[NODES] = NE2;
}

// scatter real edges only (self-loops pre-placed)
__global__ void k_scatter(const int* __restrict__ ei, int* __restrict__ cursor,
                          int* __restrict__ csr_src)
{
    int i = blockIdx.x * 256 + threadIdx.x;
    if (i >= NEDGE) return;
    int s = ei[i], d = ei[NEDGE + i];
    int pos = atomicAdd(&cursor[d], 1);
    csr_src[pos] = s;
}

// ====== Layer 1 GEMM (MFMA) + fused attention scores =====================
__global__ __launch_bounds__(256) void k_gemm1m(
    const float* __restrict__ x, const f16* __restrict__ W1p,
    const float* __restrict__ as1, const float* __restrict__ ad1,
    f16* __restrict__ xp1h, float* __restrict__ ssrc, float* __restrict__ sdst)
{
    const int wv = threadIdx.x >> 6, lane = threadIdx.x & 63;
    const int l15 = lane & 15, quad = lane >> 4;
    const int rowtile = blockIdx.x * 4 + wv;
    if (rowtile >= MTILES) return;
    const int rowbase = rowtile * 16;

    f16x8 afrag[4];
    const float* xrow = x + (rowbase + l15) * INDIM + quad * 8;
#pragma unroll
    for (int kb = 0; kb < 4; ++kb) {
        float4 u0 = *(const float4*)(xrow + kb * 32);
        float4 u1 = *(const float4*)(xrow + kb * 32 + 4);
        f16x8 a;
        a[0] = (f16)u0.x; a[1] = (f16)u0.y; a[2] = (f16)u0.z; a[3] = (f16)u0.w;
        a[4] = (f16)u1.x; a[5] = (f16)u1.y; a[6] = (f16)u1.z; a[7] = (f16)u1.w;
        afrag[kb] = a;
    }

    const f16x8* Wf = (const f16x8*)W1p;
    f32x4 acc[16];
#pragma unroll
    for (int ct = 0; ct < 16; ++ct) acc[ct] = (f32x4){0.f, 0.f, 0.f, 0.f};
#pragma unroll
    for (int ct = 0; ct < 16; ++ct) {
#pragma unroll
        for (int kb = 0; kb < 4; ++kb) {
            f16x8 b = Wf[(ct * 4 + kb) * 64 + lane];
            acc[ct] = __builtin_amdgcn_mfma_f32_16x16x32_f16(afrag[kb], b, acc[ct], 0, 0, 0);
        }
    }
    // stores: C/D col = ct*16 + l15, row = quad*4 + r
    const int orow = rowbase + quad * 4;
#pragma unroll
    for (int ct = 0; ct < 16; ++ct) {
#pragma unroll
        for (int r = 0; r < 4; ++r)
            xp1h[(orow + r) * F1 + ct * 16 + l15] = (f16)acc[ct][r];
    }
    // fused scores
    float ps[4][4], pd[4][4];
#pragma unroll
    for (int h = 0; h < 4; ++h)
#pragma unroll
        for (int r = 0; r < 4; ++r) { ps[h][r] = 0.f; pd[h][r] = 0.f; }
#pragma unroll
    for (int ct = 0; ct < 16; ++ct) {
        float av = as1[ct * 16 + l15];
        float dv = ad1[ct * 16 + l15];
        int h = ct >> 2;
#pragma unroll
        for (int r = 0; r < 4; ++r) {
            ps[h][r] = fmaf(acc[ct][r], av, ps[h][r]);
            pd[h][r] = fmaf(acc[ct][r], dv, pd[h][r]);
        }
    }
#pragma unroll
    for (int off = 8; off; off >>= 1) {
#pragma unroll
        for (int h = 0; h < 4; ++h)
#pragma unroll
            for (int r = 0; r < 4; ++r) {
                ps[h][r] += __shfl_xor(ps[h][r], off);
                pd[h][r] += __shfl_xor(pd[h][r], off);
            }
    }
    if (l15 == 0) {
#pragma unroll
        for (int r = 0; r < 4; ++r) {
            int row = orow + r;
            float4 vs = {ps[0][r], ps[1][r], ps[2][r], ps[3][r]};
            float4 vd = {pd[0][r], pd[1][r], pd[2][r], pd[3][r]};
            ((float4*)ssrc)[row] = vs;
            ((float4*)sdst)[row] = vd;
        }
    }
}

// ===== Layer 1 fused softmax+aggregate: ONE wave per node =================
// chunk = 16 edges. Phase A: lane (eq=l&15, ph=l>>4) -> exp(edge eq, head ph).
// Phase B: 4 edges in flight: group g=l>>4 handles edge p+g; 16 lanes x 32B
// (two f16x8 units: sub and sub+16) cover the 512B row. Pads with ex=0.
__global__ __launch_bounds__(256) void k_agg1(
    const int* __restrict__ row_ptr, const int* __restrict__ csr_src,
    const float* __restrict__ ssrc, const float* __restrict__ sdst,
    const f16* __restrict__ xp1h, const float* __restrict__ bias,
    f16* __restrict__ hbuf)
{
    const int wv = threadIdx.x >> 6, l = threadIdx.x & 63;
    const int n = blockIdx.x * 4 + wv;
    const int eq = l & 15, ph = l >> 4;        // phase-A role
    const int g  = l >> 4, sub = l & 15;       // phase-B role
    const int sel_lo = (sub >> 3) << 4;        // head of unit sub (0/1) -> lane blk
    const int sel_hi = (2 + (sub >> 3)) << 4;  // head of unit sub+16 (2/3)
    const float sd = sdst[n * HEADS + ph];
    const int jbeg = row_ptr[n], jend = row_ptr[n + 1];
    const f16x8* xv = (const f16x8*)xp1h;

    float den = 0.f;
    float alo[8] = {0.f,0.f,0.f,0.f,0.f,0.f,0.f,0.f};
    float ahi[8] = {0.f,0.f,0.f,0.f,0.f,0.f,0.f,0.f};
    for (int base = jbeg; base < jend; base += 16) {
        int c = jend - base; if (c > 16) c = 16;
        int s = 0; float ex = 0.f;
        if (eq < c) {
            s = csr_src[base + eq];
            float e = ssrc[s * HEADS + ph] + sd;
            e = e > 0.f ? e : 0.2f * e;
            ex = __expf(e);
        }
        den += ex;
        int p = 0;
        for (; p + 7 < c; p += 8) {            // 8 edges: groups (p..p+3),(p+4..p+7)
            int ea = p + g, eb = p + 4 + g;
            int   sa  = __shfl(s, ea),          sb  = __shfl(s, eb);
            float aal = __shfl(ex, ea | sel_lo), aah = __shfl(ex, ea | sel_hi);
            float abl = __shfl(ex, eb | sel_lo), abh = __shfl(ex, eb | sel_hi);
            f16x8 va0 = xv[sa * 32 + sub];
            f16x8 va1 = xv[sa * 32 + sub + 16];
            f16x8 vb0 = xv[sb * 32 + sub];
            f16x8 vb1 = xv[sb * 32 + sub + 16];
#pragma unroll
            for (int j = 0; j < 8; ++j) {
                alo[j] = fmaf(aal, (float)va0[j], alo[j]);
                ahi[j] = fmaf(aah, (float)va1[j], ahi[j]);
            }
#pragma unroll
            for (int j = 0; j < 8; ++j) {
                alo[j] = fmaf(abl, (float)vb0[j], alo[j]);
                ahi[j] = fmaf(abh, (float)vb1[j], ahi[j]);
            }
        }
        for (; p < c; p += 4) {                // 4 edges, ex=0 pads (s=0 rows L2-hot)
            int ea = p + g;
            int   sa  = __shfl(s, ea);
            float aal = __shfl(ex, ea | sel_lo), aah = __shfl(ex, ea | sel_hi);
            f16x8 va0 = xv[sa * 32 + sub];
            f16x8 va1 = xv[sa * 32 + sub + 16];
#pragma unroll
            for (int j = 0; j < 8; ++j) {
                alo[j] = fmaf(aal, (float)va0[j], alo[j]);
                ahi[j] = fmaf(aah, (float)va1[j], ahi[j]);
            }
        }
    }
    // per-head denominator: reduce within 16-lane groups -> head ph total
#pragma unroll
    for (int off = 8; off; off >>= 1) den += __shfl_xor(den, off);
    const float dl = __shfl(den, sel_lo);
    const float dh = __shfl(den, sel_hi);
    const float rdl = 1.f / (dl + 1e-16f);
    const float rdh = 1.f / (dh + 1e-16f);
    // combine the 4 edge-groups
#pragma unroll
    for (int j = 0; j < 8; ++j) {
        alo[j] += __shfl_xor(alo[j], 16); alo[j] += __shfl_xor(alo[j], 32);
        ahi[j] += __shfl_xor(ahi[j], 16); ahi[j] += __shfl_xor(ahi[j], 32);
    }
    if (g == 0) {
        const float4* b4 = (const float4*)bias;
        float4 bl0 = b4[sub * 2],        bl1 = b4[sub * 2 + 1];
        float4 bh0 = b4[(sub + 16) * 2], bh1 = b4[(sub + 16) * 2 + 1];
        f16x8 olo, ohi;
        float v;
        v = fmaf(alo[0], rdl, bl0.x); olo[0] = (f16)(v > 0.f ? v : 0.f);
        v = fmaf(alo[1], rdl, bl0.y); olo[1] = (f16)(v > 0.f ? v : 0.f);
        v = fmaf(alo[2], rdl, bl0.z); olo[2] = (f16)(v > 0.f ? v : 0.f);
        v = fmaf(alo[3], rdl, bl0.w); olo[3] = (f16)(v > 0.f ? v : 0.f);
        v = fmaf(alo[4], rdl, bl1.x); olo[4] = (f16)(v > 0.f ? v : 0.f);
        v = fmaf(alo[5], rdl, bl1.y); olo[5] = (f16)(v > 0.f ? v : 0.f);
        v = fmaf(alo[6], rdl, bl1.z); olo[6] = (f16)(v > 0.f ? v : 0.f);
        v = fmaf(alo[7], rdl, bl1.w); olo[7] = (f16)(v > 0.f ? v : 0.f);
        v = fmaf(ahi[0], rdh, bh0.x); ohi[0] = (f16)(v > 0.f ? v : 0.f);
        v = fmaf(ahi[1], rdh, bh0.y); ohi[1] = (f16)(v > 0.f ? v : 0.f);
        v = fmaf(ahi[2], rdh, bh0.z); ohi[2] = (f16)(v > 0.f ? v : 0.f);
        v = fmaf(ahi[3], rdh, bh0.w); ohi[3] = (f16)(v > 0.f ? v : 0.f);
        v = fmaf(ahi[4], rdh, bh1.x); ohi[4] = (f16)(v > 0.f ? v : 0.f);
        v = fmaf(ahi[5], rdh, bh1.y); ohi[5] = (f16)(v > 0.f ? v : 0.f);
        v = fmaf(ahi[6], rdh, bh1.z); ohi[6] = (f16)(v > 0.f ? v : 0.f);
        v = fmaf(ahi[7], rdh, bh1.w); ohi[7] = (f16)(v > 0.f ? v : 0.f);
        ((f16x8*)hbuf)[n * 32 + sub] = olo;
        ((f16x8*)hbuf)[n * 32 + sub + 16] = ohi;
    }
}

// ====== Layer 2 GEMM (MFMA) + fused scores ================================
__global__ __launch_bounds__(256) void k_gemm2m(
    const f16* __restrict__ hbuf, const f16* __restrict__ W2p,
    const float* __restrict__ as2, const float* __restrict__ ad2,
    f16* __restrict__ xp2h, float* __restrict__ ssrc, float* __restrict__ sdst)
{
    const int wv = threadIdx.x >> 6, lane = threadIdx.x & 63;
    const int l15 = lane & 15, quad = lane >> 4;
    const int rowtile = blockIdx.x * 4 + wv;
    if (rowtile >= MTILES) return;
    const int rowbase = rowtile * 16;

    const f16x8* Wf = (const f16x8*)W2p;
    f32x4 acc[4];
#pragma unroll
    for (int ct = 0; ct < 4; ++ct) acc[ct] = (f32x4){0.f, 0.f, 0.f, 0.f};
    const f16* hrow = hbuf + (rowbase + l15) * F1 + quad * 8;
#pragma unroll
    for (int kb = 0; kb < 8; ++kb) {
        f16x8 a = *(const f16x8*)(hrow + kb * 32);
#pragma unroll
        for (int ct = 0; ct < 4; ++ct) {
            f16x8 b = Wf[(ct * 8 + kb) * 64 + lane];
            acc[ct] = __builtin_amdgcn_mfma_f32_16x16x32_f16(a, b, acc[ct], 0, 0, 0);
        }
    }
    const int orow = rowbase + quad * 4;
#pragma unroll
    for (int ct = 0; ct < 4; ++ct) {
#pragma unroll
        for (int r = 0; r < 4; ++r)
            xp2h[(orow + r) * OUTD + ct * 16 + l15] = (f16)acc[ct][r];
    }
    float ps[4] = {0.f,0.f,0.f,0.f}, pd[4] = {0.f,0.f,0.f,0.f};
#pragma unroll
    for (int ct = 0; ct < 4; ++ct) {
        float av = as2[ct * 16 + l15];
        float dv = ad2[ct * 16 + l15];
#pragma unroll
        for (int r = 0; r < 4; ++r) {
            ps[r] = fmaf(acc[ct][r], av, ps[r]);
            pd[r] = fmaf(acc[ct][r], dv, pd[r]);
        }
    }
#pragma unroll
    for (int off = 8; off; off >>= 1) {
#pragma unroll
        for (int r = 0; r < 4; ++r) {
            ps[r] += __shfl_xor(ps[r], off);
            pd[r] += __shfl_xor(pd[r], off);
        }
    }
    if (l15 == 0) {
#pragma unroll
        for (int r = 0; r < 4; ++r) {
            ssrc[orow + r] = ps[r];
            sdst[orow + r] = pd[r];
        }
    }
}

// ===== Layer 2 fused softmax+aggregate+bias -> d_out: b128 gather =====
// chunk = 64 edges; phase B 2-step unroll (2 gathers in flight per lane)
__global__ __launch_bounds__(256) void k_agg2(
    const int* __restrict__ row_ptr, const int* __restrict__ csr_src,
    const float* __restrict__ ssrc, const float* __restrict__ sdst,
    const f16* __restrict__ xp2h, const float* __restrict__ bias,
    float* __restrict__ out)
{
    const int wv = threadIdx.x >> 6, l = threadIdx.x & 63;
    const int n = blockIdx.x * 4 + wv;
    const int grp = l >> 3, sub = l & 7;
    const float sd = sdst[n];
    const int jbeg = row_ptr[n], jend = row_ptr[n + 1];
    const f16x8* xv = (const f16x8*)xp2h;

    float den = 0.f;
    float acc[8] = {0.f,0.f,0.f,0.f,0.f,0.f,0.f,0.f};
    for (int base = jbeg; base < jend; base += 64) {
        int c = jend - base; if (c > 64) c = 64;
        int s = 0; float ex = 0.f;
        if (l < c) {
            s = csr_src[base + l];
            float e = ssrc[s] + sd;
            e = e > 0.f ? e : 0.2f * e;
            ex = __expf(e);
        }
        den += ex;
        int i = 0;
        for (; 8 * (i + 1) < c; i += 2) {
            int ea = 8 * i + grp, eb = 8 * i + 8 + grp;
            int   sa = __shfl(s, ea),  sb = __shfl(s, eb);
            float aa = __shfl(ex, ea), ab = __shfl(ex, eb);
            f16x8 va = xv[sa * 8 + sub];
            f16x8 vb = xv[sb * 8 + sub];
#pragma unroll
            for (int j = 0; j < 8; ++j) acc[j] = fmaf(aa, (float)va[j], acc[j]);
#pragma unroll
            for (int j = 0; j < 8; ++j) acc[j] = fmaf(ab, (float)vb[j], acc[j]);
        }
        for (; 8 * i < c; ++i) {
            int eidx = 8 * i + grp;
            int   se = __shfl(s, eidx);
            float ae = __shfl(ex, eidx);
            f16x8 v = xv[se * 8 + sub];
#pragma unroll
            for (int j = 0; j < 8; ++j) acc[j] = fmaf(ae, (float)v[j], acc[j]);
        }
    }
#pragma unroll
    for (int off = 32; off; off >>= 1) den += __shfl_xor(den, off);
    const float rd = 1.f / (den + 1e-16f);
#pragma unroll
    for (int j = 0; j < 8; ++j) {
        acc[j] += __shfl_xor(acc[j], 8);
        acc[j] += __shfl_xor(acc[j], 16);
        acc[j] += __shfl_xor(acc[j], 32);
    }
    if (grp == 0) {
        const float4* b4 = (const float4*)bias;
        float4 ba = b4[sub * 2], bb = b4[sub * 2 + 1];
        float4 o0, o1;
        o0.x = fmaf(acc[0], rd, ba.x); o0.y = fmaf(acc[1], rd, ba.y);
        o0.z = fmaf(acc[2], rd, ba.z); o0.w = fmaf(acc[3], rd, ba.w);
        o1.x = fmaf(acc[4], rd, bb.x); o1.y = fmaf(acc[5], rd, bb.y);
        o1.z = fmaf(acc[6], rd, bb.z); o1.w = fmaf(acc[7], rd, bb.w);
        float4* ov = (float4*)out + n * 16 + sub * 2;
        ov[0] = o0; ov[1] = o1;
    }
}

extern "C" void kernel_launch(void* const* d_in, const int* in_sizes, int n_in,
                              void* d_out, int out_size, void* d_ws, size_t ws_size,
                              hipStream_t stream)
{
    (void)in_sizes; (void)n_in; (void)out_size; (void)ws_size;
    const float* x   = (const float*)d_in[0];
    const int*   ei  = (const int*)d_in[1];
    const float* W1  = (const float*)d_in[2];
    const float* as1 = (const float*)d_in[3];
    const float* ad1 = (const float*)d_in[4];
    const float* b1  = (const float*)d_in[5];
    const float* W2  = (const float*)d_in[6];
    const float* as2 = (const float*)d_in[7];
    const float* ad2 = (const float*)d_in[8];
    const float* b2  = (const float*)d_in[9];
    float* out = (float*)d_out;

    // workspace layout (~58 MB)
    f16* xp1h   = (f16*)d_ws;                              // N*256 f16 (25.6 MB)
    f16* hbuf   = xp1h + (size_t)NODES * F1;               // N*256 f16 (25.6 MB)
    f16* W1p    = hbuf + (size_t)NODES * F1;               // 32768 f16
    f16* W2p    = W1p + 32768;                             // 16384 f16
    float* ssrc1 = (float*)(W2p + 16384);                  // N*4
    float* sdst1 = ssrc1 + (size_t)NODES * HEADS;          // N*4
    float* ssrc2 = sdst1 + (size_t)NODES * HEADS;          // N
    float* sdst2 = ssrc2 + (size_t)NODES;                  // N
    int* deg     = (int*)(sdst2 + (size_t)NODES);          // N
    int* row_ptr = deg + NODES;                            // N+1
    int* bsum    = row_ptr + NODES + 1;                    // 256
    int* cursor  = bsum + 256;                             // N
    int* csr_src = cursor + NODES;                         // NE2
    f16* xp2h    = xp1h;   // alias: xp1h dead after k_agg1

    // ---- CSR build (dst-sorted) + W pre-swizzle ----
    hipMemsetAsync(deg, 0, sizeof(int) * NODES, stream);
    k_histprep<<<3125 + 192, 256, 0, stream>>>(ei, deg, W1, W2, W1p, W2p);
    k_scan1<<<NBLK_SCAN, 256, 0, stream>>>(deg, row_ptr, bsum);
    k_scan3<<<NBLK_SCAN, 256, 0, stream>>>(row_ptr, bsum, cursor, csr_src);
    k_scatter<<<(NEDGE + 255) / 256, 256, 0, stream>>>(ei, cursor, csr_src);

    // ---- layer 1 ----
    k_gemm1m<<<(MTILES + 3) / 4, 256, 0, stream>>>(x, W1p, as1, ad1,
                                                   xp1h, ssrc1, sdst1);
    k_agg1<<<NODES / 4, 256, 0, stream>>>(row_ptr, csr_src, ssrc1, sdst1,
                                          xp1h, b1, hbuf);

    // ---- layer 2 ----
    k_gemm2m<<<(MTILES + 3) / 4, 256, 0, stream>>>(hbuf, W2p, as2, ad2,
                                                   xp2h, ssrc2, sdst2);
    k_agg2<<<NODES / 4, 256, 0, stream>>>(row_ptr, csr_src, ssrc2, sdst2,
                                          xp2h, b2, out);
}